// Round 10
// baseline (249.312 us; speedup 1.0000x reference)
//
#include <hip/hip_runtime.h>
#include <hip/hip_bf16.h>

#define NB 4
#define NC 512
#define NS 4096
#define NH 8
#define HD 64
#define NG 32
#define CPG 16
#define QKC 1024   // Q+K channels in qk buffer
#define CQF 0.18033688f  // 0.125 * log2(e), folded into Q weights

typedef __attribute__((ext_vector_type(8))) short bf16x8;
typedef __attribute__((ext_vector_type(4))) float f32x4;
typedef __attribute__((ext_vector_type(16))) float f32x16;

__device__ __forceinline__ unsigned short f2bf(float f) {
  union { float f; unsigned int u; } v; v.f = f;
  unsigned int r = v.u + 0x7FFFu + ((v.u >> 16) & 1u);
  return (unsigned short)(r >> 16);
}

__device__ __forceinline__ unsigned short f2bf_rn(float f) {
  union { __hip_bfloat16 h; unsigned short u; } cv;
  cv.h = __float2bfloat16(f);
  return cv.u;
}

// async global->LDS, 16B per lane. LDS base must be wave-uniform; source is per-lane.
__device__ __forceinline__ void gload16(const unsigned short* g, unsigned short* s) {
  __builtin_amdgcn_global_load_lds(
      (const __attribute__((address_space(1))) unsigned int*)g,
      (__attribute__((address_space(3))) unsigned int*)s, 16, 0, 0);
}

// ---------------- K0: weight prep: fp32 -> bf16, scale first scale_end8*8 elems ----------------
__global__ __launch_bounds__(256) void wprep_k(const float* __restrict__ src,
                                               unsigned short* __restrict__ dst,
                                               int n8, int scale_end8, float scale) {
  int i = blockIdx.x * 256 + threadIdx.x;
  if (i >= n8) return;
  const float4* s = (const float4*)src + (size_t)i * 2;
  float4 a = s[0], b = s[1];
  float sc = (i < scale_end8) ? scale : 1.0f;
  ushort4 u0 = make_ushort4(f2bf_rn(a.x * sc), f2bf_rn(a.y * sc),
                            f2bf_rn(a.z * sc), f2bf_rn(a.w * sc));
  ushort4 u1 = make_ushort4(f2bf_rn(b.x * sc), f2bf_rn(b.y * sc),
                            f2bf_rn(b.z * sc), f2bf_rn(b.w * sc));
  uint4 o;
  o.x = (unsigned)u0.x | ((unsigned)u0.y << 16);
  o.y = (unsigned)u0.z | ((unsigned)u0.w << 16);
  o.z = (unsigned)u1.x | ((unsigned)u1.y << 16);
  o.w = (unsigned)u1.z | ((unsigned)u1.w << 16);
  *((uint4*)dst + i) = o;
}

// ---------------- K1: GroupNorm partial stats: 512 blocks, one quarter-group each ----------------
__global__ __launch_bounds__(256) void gn_stats_k(const float* __restrict__ x,
                                                  float* __restrict__ pstats) {
  int bgq = blockIdx.x;
  const float4* xp = (const float4*)(x + (size_t)bgq * (CPG * NS / 4));
  float s = 0.f, s2 = 0.f;
  #pragma unroll 4
  for (int i = threadIdx.x; i < CPG * NS / 16; i += 256) {
    float4 v = xp[i];
    s  += v.x + v.y + v.z + v.w;
    s2 += v.x * v.x + v.y * v.y + v.z * v.z + v.w * v.w;
  }
  #pragma unroll
  for (int off = 32; off > 0; off >>= 1) {
    s  += __shfl_down(s, off);
    s2 += __shfl_down(s2, off);
  }
  __shared__ float rs[4], rs2[4];
  int wid = threadIdx.x >> 6;
  if ((threadIdx.x & 63) == 0) { rs[wid] = s; rs2[wid] = s2; }
  __syncthreads();
  if (threadIdx.x == 0) {
    pstats[bgq * 2]     = rs[0] + rs[1] + rs[2] + rs[3];
    pstats[bgq * 2 + 1] = rs2[0] + rs2[1] + rs2[2] + rs2[3];
  }
}

// ---------------- K2: normalize + transpose -> ht[b][s][c] (bf16); combines partial stats ----------------
__global__ __launch_bounds__(256) void gn_apply_k(const float* __restrict__ x,
                                                  const float* __restrict__ pstats,
                                                  const float* __restrict__ nw,
                                                  const float* __restrict__ nb,
                                                  unsigned short* __restrict__ ht) {
  int st = blockIdx.x, ct = blockIdx.y, b = blockIdx.z;
  int c0 = ct * 64, s0 = st * 64;
  __shared__ unsigned short lds[64][72];
  for (int idx = threadIdx.x; idx < 1024; idx += 256) {
    int row = idx >> 4, c4 = idx & 15;
    int c = c0 + row;
    int gi = (b * NG + (c >> 4)) * 4;
    const float4* pq = (const float4*)(pstats + gi * 2);
    float4 p01 = pq[0], p23 = pq[1];
    float sum = p01.x + p01.z + p23.x + p23.z;
    float ssq = p01.y + p01.w + p23.y + p23.w;
    float inv_n = 1.0f / (CPG * NS);
    float mu = sum * inv_n;
    float var = ssq * inv_n - mu * mu;
    float rstd = rsqrtf(var + 1e-5f);
    float sw = nw[c] * rstd;
    float sb = nb[c] - mu * sw;
    float4 v = *(const float4*)(x + ((size_t)b * NC + c) * NS + s0 + c4 * 4);
    ushort4 u = make_ushort4(f2bf(v.x * sw + sb), f2bf(v.y * sw + sb),
                             f2bf(v.z * sw + sb), f2bf(v.w * sw + sb));
    *(ushort4*)&lds[row][c4 * 4] = u;
  }
  __syncthreads();
  for (int idx = threadIdx.x; idx < 1024; idx += 256) {
    int i = idx >> 4, ch = idx & 15;
    ushort4 u = make_ushort4(lds[ch * 4 + 0][i], lds[ch * 4 + 1][i],
                             lds[ch * 4 + 2][i], lds[ch * 4 + 3][i]);
    *(ushort4*)(ht + ((size_t)b * NS + s0 + i) * NC + c0 + ch * 4) = u;
  }
}

// ---------------- K3: QKV GEMM, global_load_lds staging (BK=64, XOR-swizzled LDS) ----------------
__global__ __launch_bounds__(256) void qkv_gemm_k(const unsigned short* __restrict__ ht,
                                                  const unsigned short* __restrict__ wqb,
                                                  const float* __restrict__ bq,
                                                  unsigned short* __restrict__ qk,
                                                  unsigned short* __restrict__ vt) {
  int b = blockIdx.z;
  int m0 = blockIdx.x * 128, n0 = blockIdx.y * 128;  // m = s, n = o
  __shared__ unsigned short alds[128 * 64];
  __shared__ unsigned short blds[128 * 64];
  const unsigned short* A = ht + (size_t)b * NS * NC;
  int tid = threadIdx.x;
  int l = tid & 63, w = tid >> 6;
  int wr = w >> 1, wc = w & 1;
  int lm = l & 15, lg = l >> 4;
  int lrow = l >> 3, lcb = l & 7;
  f32x4 acc[4][4];
  #pragma unroll
  for (int mi = 0; mi < 4; mi++)
    #pragma unroll
    for (int ni = 0; ni < 4; ni++) acc[mi][ni] = (f32x4){0.f, 0.f, 0.f, 0.f};

  for (int k0 = 0; k0 < NC; k0 += 64) {
    #pragma unroll
    for (int j = 0; j < 4; j++) {
      int row = w * 32 + j * 8 + lrow;
      int scb = lcb ^ (row & 7);
      gload16(A   + (size_t)(m0 + row) * NC + k0 + scb * 8, &alds[(w * 4 + j) * 512]);
      gload16(wqb + (size_t)(n0 + row) * NC + k0 + scb * 8, &blds[(w * 4 + j) * 512]);
    }
    __syncthreads();
    #pragma unroll
    for (int ks = 0; ks < 2; ks++) {
      bf16x8 af[4], bfr[4];
      #pragma unroll
      for (int mi = 0; mi < 4; mi++) {
        int row = wr * 64 + mi * 16 + lm;
        af[mi] = *(const bf16x8*)&alds[((row << 6) + (ks << 5) + (lg << 3)) ^ ((row & 7) << 3)];
      }
      #pragma unroll
      for (int ni = 0; ni < 4; ni++) {
        int row = wc * 64 + ni * 16 + lm;
        bfr[ni] = *(const bf16x8*)&blds[((row << 6) + (ks << 5) + (lg << 3)) ^ ((row & 7) << 3)];
      }
      #pragma unroll
      for (int mi = 0; mi < 4; mi++)
        #pragma unroll
        for (int ni = 0; ni < 4; ni++)
          acc[mi][ni] = __builtin_amdgcn_mfma_f32_16x16x32_bf16(af[mi], bfr[ni], acc[mi][ni], 0, 0, 0);
    }
    __syncthreads();
  }
  if (n0 < QKC) {
    #pragma unroll
    for (int mi = 0; mi < 4; mi++) {
      #pragma unroll
      for (int ni = 0; ni < 4; ni++) {
        int o = n0 + wc * 64 + ni * 16 + lm;
        float bias = bq[o];
        if (o < NC) bias *= CQF;  // Q rows: weight pre-scaled, bias scaled to match
        #pragma unroll
        for (int q = 0; q < 4; q++) {
          int s = m0 + wr * 64 + mi * 16 + lg * 4 + q;
          qk[((size_t)b * NS + s) * QKC + o] = f2bf(acc[mi][ni][q] + bias);
        }
      }
    }
  } else {
    #pragma unroll
    for (int mi = 0; mi < 4; mi++) {
      int s0 = m0 + wr * 64 + mi * 16 + lg * 4;
      #pragma unroll
      for (int ni = 0; ni < 4; ni++) {
        int o = n0 + wc * 64 + ni * 16 + lm;
        float bias = bq[o];
        int dg = o - QKC;  // 0..511 == h*64+d
        ushort4 u = make_ushort4(f2bf(acc[mi][ni][0] + bias), f2bf(acc[mi][ni][1] + bias),
                                 f2bf(acc[mi][ni][2] + bias), f2bf(acc[mi][ni][3] + bias));
        *(ushort4*)(vt + ((size_t)b * NC + dg) * NS + s0) = u;
      }
    }
  }
}

// ---------------- K4: flash attention (32x32x16 MFMA, deferred softmax pipeline) ----------------
// Round t: QK(t) MFMAs -> SAN; exp2+cvt of SAP=sa(t-1) (independent of QK(t) -> scheduler
// overlaps the trans burst with the MFMA drain); PV(t-1) from register P + V(t-1) regs.
__global__ __launch_bounds__(256) void attn_k(const unsigned short* __restrict__ qk,
                                              const unsigned short* __restrict__ vt,
                                              unsigned short* __restrict__ ob) {
  int qt = blockIdx.x, h = blockIdx.y, b = blockIdx.z;
  int tid = threadIdx.x;
  int l = tid & 63, w = tid >> 6;
  int l31 = l & 31, hi = l >> 5;
  __shared__ unsigned short slds[16384];  // [buf:2][K|V][64x64 shorts] = 32 KB
  const unsigned short* qkb = qk + (size_t)b * NS * QKC;
  const unsigned short* vtb = vt + ((size_t)b * NC + h * HD) * NS;
  int iw = qt * 128 + w * 32;

  bf16x8 fq[4];
  #pragma unroll
  for (int kk = 0; kk < 4; kk++)
    fq[kk] = *(const bf16x8*)(qkb + (size_t)(iw + l31) * QKC + h * HD + kk * 16 + hi * 8);

  bf16x8 ones;
  #pragma unroll
  for (int e = 0; e < 8; e++) ones[e] = (short)0x3F80;

  int rb = (((l31 << 6) + (hi << 3)) ^ ((l31 & 7) << 3));
  int rbk[4] = { rb, rb ^ 16, rb ^ 32, rb ^ 48 };

  int sr = tid >> 3, sch = (tid & 7) * 8;
  const unsigned short* kp0 = qkb + NC + h * HD + (size_t)sr * QKC + sch;
  const unsigned short* kp1 = kp0 + (size_t)32 * QKC;
  const unsigned short* vp0 = vtb + (size_t)sr * NS + sch;
  const unsigned short* vp1 = vp0 + (size_t)32 * NS;
  int dk0 = (((sr << 6) + sch) ^ ((sr & 7) << 3));
  int dk1 = ((((sr + 32) << 6) + sch) ^ ((sr & 7) << 3));

  f32x16 acc_o0 = {}, acc_o1 = {}, acc_l = {};
  f32x16 saA0, saA1, saB0, saB1;   // raw-score ping-pong (deferred softmax)
  bf16x8 vA[8], vB[8];             // V-fragment ping-pong

  // prologue: tile0 -> buf0; prefetch tile1
  uint4 rk0 = *(const uint4*)kp0, rk1 = *(const uint4*)kp1;
  uint4 rv0 = *(const uint4*)vp0, rv1 = *(const uint4*)vp1;
  *(uint4*)&slds[dk0] = rk0;        *(uint4*)&slds[dk1] = rk1;
  *(uint4*)&slds[4096 + dk0] = rv0; *(uint4*)&slds[4096 + dk1] = rv1;
  kp0 += (size_t)64 * QKC; kp1 += (size_t)64 * QKC; vp0 += 64; vp1 += 64;
  rk0 = *(const uint4*)kp0; rk1 = *(const uint4*)kp1;
  rv0 = *(const uint4*)vp0; rv1 = *(const uint4*)vp1;
  __syncthreads();

  // round 0 (no softmax/PV yet): stage tile1 -> buf1; prefetch tile2; QK(0); V(0)->vA
  {
    *(uint4*)&slds[8192 + dk0] = rk0;        *(uint4*)&slds[8192 + dk1] = rk1;
    *(uint4*)&slds[8192 + 4096 + dk0] = rv0; *(uint4*)&slds[8192 + 4096 + dk1] = rv1;
    kp0 += (size_t)64 * QKC; kp1 += (size_t)64 * QKC; vp0 += 64; vp1 += 64;
    rk0 = *(const uint4*)kp0; rk1 = *(const uint4*)kp1;
    rv0 = *(const uint4*)vp0; rv1 = *(const uint4*)vp1;
    saA0 = (f32x16){}; saA1 = (f32x16){};
    __builtin_amdgcn_s_setprio(1);
    #pragma unroll
    for (int kk = 0; kk < 4; kk++) {
      bf16x8 ak = *(const bf16x8*)&slds[rbk[kk]];
      saA0 = __builtin_amdgcn_mfma_f32_32x32x16_bf16(ak, fq[kk], saA0, 0, 0, 0);
    }
    #pragma unroll
    for (int kk = 0; kk < 4; kk++) {
      bf16x8 ak = *(const bf16x8*)&slds[rbk[kk] + 2048];
      saA1 = __builtin_amdgcn_mfma_f32_32x32x16_bf16(ak, fq[kk], saA1, 0, 0, 0);
    }
    __builtin_amdgcn_s_setprio(0);
    #pragma unroll
    for (int kk = 0; kk < 4; kk++) {
      vA[kk]     = *(const bf16x8*)&slds[4096 + rbk[kk]];
      vA[kk + 4] = *(const bf16x8*)&slds[4096 + rbk[kk] + 2048];
    }
    __syncthreads();
  }

  #define CVTSW(S0, q, DST) {                                                       \
    unsigned X0, X1, Y0, Y1;                                                        \
    asm("v_cvt_pk_bf16_f32 %0, %1, %2" : "=v"(X0) : "v"(S0[q*8+0]), "v"(S0[q*8+1]));\
    asm("v_cvt_pk_bf16_f32 %0, %1, %2" : "=v"(X1) : "v"(S0[q*8+2]), "v"(S0[q*8+3]));\
    asm("v_cvt_pk_bf16_f32 %0, %1, %2" : "=v"(Y0) : "v"(S0[q*8+4]), "v"(S0[q*8+5]));\
    asm("v_cvt_pk_bf16_f32 %0, %1, %2" : "=v"(Y1) : "v"(S0[q*8+6]), "v"(S0[q*8+7]));\
    asm("v_permlane32_swap_b32 %0, %1" : "+v"(X0), "+v"(Y0));                       \
    asm("v_permlane32_swap_b32 %0, %1" : "+v"(X1), "+v"(Y1));                       \
    union { unsigned u[4]; bf16x8 v; } pu = {{X0, X1, Y0, Y1}};                     \
    DST = pu.v; }

  // ROUND t: stage(t+1)->BUF^1; prefetch(t+2); QK(t)->SAN; exp2(SAP); V(t)->VN;
  //          cvt(SAP)->P; PV(t-1) = P x VP; barrier.
  #define ROUND(BUF, t, SAN0, SAN1, SAP0, SAP1, VN, VP) {                           \
    if ((t) + 1 < 64) {                                                             \
      *(uint4*)&slds[(BUF^1)*8192 + dk0] = rk0;                                     \
      *(uint4*)&slds[(BUF^1)*8192 + dk1] = rk1;                                     \
      *(uint4*)&slds[(BUF^1)*8192 + 4096 + dk0] = rv0;                              \
      *(uint4*)&slds[(BUF^1)*8192 + 4096 + dk1] = rv1;                              \
    }                                                                               \
    if ((t) + 2 < 64) {                                                             \
      kp0 += (size_t)64 * QKC; kp1 += (size_t)64 * QKC; vp0 += 64; vp1 += 64;       \
      rk0 = *(const uint4*)kp0; rk1 = *(const uint4*)kp1;                           \
      rv0 = *(const uint4*)vp0; rv1 = *(const uint4*)vp1;                           \
    }                                                                               \
    const unsigned short* Kr = &slds[(BUF)*8192];                                   \
    const unsigned short* Vr = &slds[(BUF)*8192 + 4096];                            \
    SAN0 = (f32x16){}; SAN1 = (f32x16){};                                           \
    __builtin_amdgcn_s_setprio(1);                                                  \
    _Pragma("unroll")                                                               \
    for (int kk = 0; kk < 4; kk++) {                                                \
      bf16x8 ak = *(const bf16x8*)&Kr[rbk[kk]];                                     \
      SAN0 = __builtin_amdgcn_mfma_f32_32x32x16_bf16(ak, fq[kk], SAN0, 0, 0, 0);    \
    }                                                                               \
    _Pragma("unroll")                                                               \
    for (int kk = 0; kk < 4; kk++) {                                                \
      bf16x8 ak = *(const bf16x8*)&Kr[rbk[kk] + 2048];                              \
      SAN1 = __builtin_amdgcn_mfma_f32_32x32x16_bf16(ak, fq[kk], SAN1, 0, 0, 0);    \
    }                                                                               \
    __builtin_amdgcn_s_setprio(0);                                                  \
    /* softmax of PREVIOUS tile: independent of SAN -> overlaps MFMA drain */       \
    _Pragma("unroll")                                                               \
    for (int r = 0; r < 16; r++) {                                                  \
      SAP0[r] = __builtin_amdgcn_exp2f(SAP0[r]);                                    \
      SAP1[r] = __builtin_amdgcn_exp2f(SAP1[r]);                                    \
    }                                                                               \
    _Pragma("unroll")                                                               \
    for (int kk = 0; kk < 4; kk++) {                                                \
      VN[kk]     = *(const bf16x8*)&Vr[rbk[kk]];                                    \
      VN[kk + 4] = *(const bf16x8*)&Vr[rbk[kk] + 2048];                             \
    }                                                                               \
    bf16x8 p0_, p1_, p2_, p3_;                                                      \
    CVTSW(SAP0, 0, p0_);                                                            \
    CVTSW(SAP0, 1, p1_);                                                            \
    CVTSW(SAP1, 0, p2_);                                                            \
    CVTSW(SAP1, 1, p3_);                                                            \
    __builtin_amdgcn_s_setprio(1);                                                  \
    acc_l  = __builtin_amdgcn_mfma_f32_32x32x16_bf16(p0_, ones, acc_l, 0, 0, 0);    \
    acc_o0 = __builtin_amdgcn_mfma_f32_32x32x16_bf16(p0_, VP[0], acc_o0, 0, 0, 0);  \
    acc_o1 = __builtin_amdgcn_mfma_f32_32x32x16_bf16(p0_, VP[4], acc_o1, 0, 0, 0);  \
    acc_l  = __builtin_amdgcn_mfma_f32_32x32x16_bf16(p1_, ones, acc_l, 0, 0, 0);    \
    acc_o0 = __builtin_amdgcn_mfma_f32_32x32x16_bf16(p1_, VP[1], acc_o0, 0, 0, 0);  \
    acc_o1 = __builtin_amdgcn_mfma_f32_32x32x16_bf16(p1_, VP[5], acc_o1, 0, 0, 0);  \
    acc_l  = __builtin_amdgcn_mfma_f32_32x32x16_bf16(p2_, ones, acc_l, 0, 0, 0);    \
    acc_o0 = __builtin_amdgcn_mfma_f32_32x32x16_bf16(p2_, VP[2], acc_o0, 0, 0, 0);  \
    acc_o1 = __builtin_amdgcn_mfma_f32_32x32x16_bf16(p2_, VP[6], acc_o1, 0, 0, 0);  \
    acc_l  = __builtin_amdgcn_mfma_f32_32x32x16_bf16(p3_, ones, acc_l, 0, 0, 0);    \
    acc_o0 = __builtin_amdgcn_mfma_f32_32x32x16_bf16(p3_, VP[3], acc_o0, 0, 0, 0);  \
    acc_o1 = __builtin_amdgcn_mfma_f32_32x32x16_bf16(p3_, VP[7], acc_o1, 0, 0, 0);  \
    __builtin_amdgcn_s_setprio(0);                                                  \
    __syncthreads(); }

  for (int t = 1; t < 63; t += 2) {
    ROUND(1, t,     saB0, saB1, saA0, saA1, vB, vA)
    ROUND(0, t + 1, saA0, saA1, saB0, saB1, vA, vB)
  }
  ROUND(1, 63, saB0, saB1, saA0, saA1, vB, vA)
  #undef ROUND

  // epilogue: softmax + PV of tile 63 (saB raw, vB regs)
  {
    #pragma unroll
    for (int r = 0; r < 16; r++) {
      saB0[r] = __builtin_amdgcn_exp2f(saB0[r]);
      saB1[r] = __builtin_amdgcn_exp2f(saB1[r]);
    }
    bf16x8 p0_, p1_, p2_, p3_;
    CVTSW(saB0, 0, p0_);
    CVTSW(saB0, 1, p1_);
    CVTSW(saB1, 0, p2_);
    CVTSW(saB1, 1, p3_);
    acc_l  = __builtin_amdgcn_mfma_f32_32x32x16_bf16(p0_, ones, acc_l, 0, 0, 0);
    acc_o0 = __builtin_amdgcn_mfma_f32_32x32x16_bf16(p0_, vB[0], acc_o0, 0, 0, 0);
    acc_o1 = __builtin_amdgcn_mfma_f32_32x32x16_bf16(p0_, vB[4], acc_o1, 0, 0, 0);
    acc_l  = __builtin_amdgcn_mfma_f32_32x32x16_bf16(p1_, ones, acc_l, 0, 0, 0);
    acc_o0 = __builtin_amdgcn_mfma_f32_32x32x16_bf16(p1_, vB[1], acc_o0, 0, 0, 0);
    acc_o1 = __builtin_amdgcn_mfma_f32_32x32x16_bf16(p1_, vB[5], acc_o1, 0, 0, 0);
    acc_l  = __builtin_amdgcn_mfma_f32_32x32x16_bf16(p2_, ones, acc_l, 0, 0, 0);
    acc_o0 = __builtin_amdgcn_mfma_f32_32x32x16_bf16(p2_, vB[2], acc_o0, 0, 0, 0);
    acc_o1 = __builtin_amdgcn_mfma_f32_32x32x16_bf16(p2_, vB[6], acc_o1, 0, 0, 0);
    acc_l  = __builtin_amdgcn_mfma_f32_32x32x16_bf16(p3_, ones, acc_l, 0, 0, 0);
    acc_o0 = __builtin_amdgcn_mfma_f32_32x32x16_bf16(p3_, vB[3], acc_o0, 0, 0, 0);
    acc_o1 = __builtin_amdgcn_mfma_f32_32x32x16_bf16(p3_, vB[7], acc_o1, 0, 0, 0);
  }
  #undef CVTSW

  #pragma unroll
  for (int r = 0; r < 16; r++) {
    float inv = __builtin_amdgcn_rcpf(acc_l[r]);
    int i = (r & 3) + 8 * (r >> 2) + 4 * hi;
    size_t rowo = ((size_t)b * NS + (iw + i)) * NC + h * HD;
    ob[rowo + l31]      = f2bf_rn(acc_o0[r] * inv);
    ob[rowo + 32 + l31] = f2bf_rn(acc_o1[r] * inv);
  }
}

// ---------------- K5: proj GEMM + bias + residual (global_load_lds staging, BK=64) ----------------
__global__ __launch_bounds__(256) void proj_gemm_k(const unsigned short* __restrict__ wpb,
                                                   const float* __restrict__ bp,
                                                   const unsigned short* __restrict__ obuf,
                                                   const float* __restrict__ x,
                                                   float* __restrict__ out) {
  int b = blockIdx.z;
  int m0 = blockIdx.x * 128, n0 = blockIdx.y * 128;  // m = o, n = s
  __shared__ unsigned short alds[128 * 64];
  __shared__ unsigned short blds[128 * 64];
  const unsigned short* Bt = obuf + (size_t)b * NS * NC;
  int tid = threadIdx.x;
  int l = tid & 63, w = tid >> 6;
  int wr = w >> 1, wc = w & 1;
  int lm = l & 15, lg = l >> 4;
  int lrow = l >> 3, lcb = l & 7;
  f32x4 acc[4][4];
  #pragma unroll
  for (int mi = 0; mi < 4; mi++)
    #pragma unroll
    for (int ni = 0; ni < 4; ni++) acc[mi][ni] = (f32x4){0.f, 0.f, 0.f, 0.f};

  for (int k0 = 0; k0 < NC; k0 += 64) {
    #pragma unroll
    for (int j = 0; j < 4; j++) {
      int row = w * 32 + j * 8 + lrow;
      int scb = lcb ^ (row & 7);
      gload16(wpb + (size_t)(m0 + row) * NC + k0 + scb * 8, &alds[(w * 4 + j) * 512]);
      gload16(Bt  + (size_t)(n0 + row) * NC + k0 + scb * 8, &blds[(w * 4 + j) * 512]);
    }
    __syncthreads();
    #pragma unroll
    for (int ks = 0; ks < 2; ks++) {
      bf16x8 af[4], bfr[4];
      #pragma unroll
      for (int mi = 0; mi < 4; mi++) {
        int row = wr * 64 + mi * 16 + lm;
        af[mi] = *(const bf16x8*)&alds[((row << 6) + (ks << 5) + (lg << 3)) ^ ((row & 7) << 3)];
      }
      #pragma unroll
      for (int ni = 0; ni < 4; ni++) {
        int row = wc * 64 + ni * 16 + lm;
        bfr[ni] = *(const bf16x8*)&blds[((row << 6) + (ks << 5) + (lg << 3)) ^ ((row & 7) << 3)];
      }
      #pragma unroll
      for (int mi = 0; mi < 4; mi++)
        #pragma unroll
        for (int ni = 0; ni < 4; ni++)
          acc[mi][ni] = __builtin_amdgcn_mfma_f32_16x16x32_bf16(af[mi], bfr[ni], acc[mi][ni], 0, 0, 0);
    }
    __syncthreads();
  }
  #pragma unroll
  for (int mi = 0; mi < 4; mi++) {
    #pragma unroll
    for (int q = 0; q < 4; q++) {
      int o = m0 + wr * 64 + mi * 16 + lg * 4 + q;
      float bias = bp[o];
      #pragma unroll
      for (int ni = 0; ni < 4; ni++) {
        int s = n0 + wc * 64 + ni * 16 + lm;
        size_t idx = ((size_t)b * NC + o) * NS + s;
        out[idx] = acc[mi][ni][q] + bias + x[idx];
      }
    }
  }
}

extern "C" void kernel_launch(void* const* d_in, const int* in_sizes, int n_in,
                              void* d_out, int out_size, void* d_ws, size_t ws_size,
                              hipStream_t stream) {
  const float* x  = (const float*)d_in[0];
  const float* nw = (const float*)d_in[1];
  const float* nb = (const float*)d_in[2];
  const float* wq = (const float*)d_in[3];
  const float* bq = (const float*)d_in[4];
  const float* wp = (const float*)d_in[5];
  const float* bp = (const float*)d_in[6];
  float* out = (float*)d_out;

  char* ws = (char*)d_ws;
  size_t off = 0;
  off += 1024;  // (legacy stats slot, unused)
  unsigned short* ht  = (unsigned short*)(ws + off); off += (size_t)NB * NS * NC * 2;   // 16.78 MB
  unsigned short* qk  = (unsigned short*)(ws + off); off += (size_t)NB * NS * QKC * 2;  // 33.55 MB
  unsigned short* vt  = (unsigned short*)(ws + off); off += (size_t)NB * NS * NC * 2;   // 16.78 MB
  unsigned short* wqb = (unsigned short*)(ws + off); off += (size_t)3 * NC * NC * 2;    // 1.57 MB
  unsigned short* wpb = (unsigned short*)(ws + off); off += (size_t)NC * NC * 2;        // 0.52 MB
  unsigned short* ob  = ht;          // lifetime-disjoint alias
  float* pstats = (float*)qk;        // lifetime-disjoint: used before qkv_gemm writes qk

  wprep_k<<<dim3((3 * NC * NC / 8 + 255) / 256), 256, 0, stream>>>(
      wq, wqb, 3 * NC * NC / 8, NC * NC / 8, CQF);
  wprep_k<<<dim3((NC * NC / 8 + 255) / 256), 256, 0, stream>>>(
      wp, wpb, NC * NC / 8, 0, 1.0f);
  gn_stats_k<<<dim3(NB * NG * 4), 256, 0, stream>>>(x, pstats);
  gn_apply_k<<<dim3(NS / 64, NC / 64, NB), 256, 0, stream>>>(x, pstats, nw, nb, ht);
  qkv_gemm_k<<<dim3(NS / 128, 1536 / 128, NB), 256, 0, stream>>>(ht, wqb, bq, qk, vt);
  attn_k<<<dim3(NS / 128, NH, NB), 256, 0, stream>>>(qk, vt, ob);
  proj_gemm_k<<<dim3(NC / 128, NS / 128, NB), 256, 0, stream>>>(wpb, bp, ob, x, out);
}

// Round 11
// 246.733 us; speedup vs baseline: 1.0105x; 1.0105x over previous
//
#include <hip/hip_runtime.h>
#include <hip/hip_bf16.h>

#define NB 4
#define NC 512
#define NS 4096
#define NH 8
#define HD 64
#define NG 32
#define CPG 16
#define QKC 1024   // Q+K channels in qk buffer
#define CQF 0.18033688f  // 0.125 * log2(e), folded into Q weights

typedef __attribute__((ext_vector_type(8))) short bf16x8;
typedef __attribute__((ext_vector_type(4))) float f32x4;
typedef __attribute__((ext_vector_type(16))) float f32x16;

__device__ __forceinline__ unsigned short f2bf(float f) {
  union { float f; unsigned int u; } v; v.f = f;
  unsigned int r = v.u + 0x7FFFu + ((v.u >> 16) & 1u);
  return (unsigned short)(r >> 16);
}

__device__ __forceinline__ unsigned short f2bf_rn(float f) {
  union { __hip_bfloat16 h; unsigned short u; } cv;
  cv.h = __float2bfloat16(f);
  return cv.u;
}

// async global->LDS, 16B per lane. LDS base must be wave-uniform; source is per-lane.
__device__ __forceinline__ void gload16(const unsigned short* g, unsigned short* s) {
  __builtin_amdgcn_global_load_lds(
      (const __attribute__((address_space(1))) unsigned int*)g,
      (__attribute__((address_space(3))) unsigned int*)s, 16, 0, 0);
}

// ---------------- K0: weight prep (both weight matrices in one launch) ----------------
// i < nq8: qkv_w -> wqb (first scale_end8 chunks scaled by CQF).  else: proj_w -> wpb.
__global__ __launch_bounds__(256) void wprep_k(const float* __restrict__ wq,
                                               const float* __restrict__ wp,
                                               unsigned short* __restrict__ wqb,
                                               unsigned short* __restrict__ wpb,
                                               int nq8, int np8, int scale_end8) {
  int i = blockIdx.x * 256 + threadIdx.x;
  if (i >= nq8 + np8) return;
  const float* src;
  unsigned short* dst;
  float sc;
  int j;
  if (i < nq8) { src = wq; dst = wqb; j = i; sc = (i < scale_end8) ? CQF : 1.0f; }
  else         { src = wp; dst = wpb; j = i - nq8; sc = 1.0f; }
  const float4* s = (const float4*)src + (size_t)j * 2;
  float4 a = s[0], b = s[1];
  ushort4 u0 = make_ushort4(f2bf_rn(a.x * sc), f2bf_rn(a.y * sc),
                            f2bf_rn(a.z * sc), f2bf_rn(a.w * sc));
  ushort4 u1 = make_ushort4(f2bf_rn(b.x * sc), f2bf_rn(b.y * sc),
                            f2bf_rn(b.z * sc), f2bf_rn(b.w * sc));
  uint4 o;
  o.x = (unsigned)u0.x | ((unsigned)u0.y << 16);
  o.y = (unsigned)u0.z | ((unsigned)u0.w << 16);
  o.z = (unsigned)u1.x | ((unsigned)u1.y << 16);
  o.w = (unsigned)u1.z | ((unsigned)u1.w << 16);
  *((uint4*)dst + j) = o;
}

// ---------------- K1: GroupNorm partial stats: 512 blocks, one quarter-group each ----------------
__global__ __launch_bounds__(256) void gn_stats_k(const float* __restrict__ x,
                                                  float* __restrict__ pstats) {
  int bgq = blockIdx.x;
  const float4* xp = (const float4*)(x + (size_t)bgq * (CPG * NS / 4));
  float s = 0.f, s2 = 0.f;
  #pragma unroll 4
  for (int i = threadIdx.x; i < CPG * NS / 16; i += 256) {
    float4 v = xp[i];
    s  += v.x + v.y + v.z + v.w;
    s2 += v.x * v.x + v.y * v.y + v.z * v.z + v.w * v.w;
  }
  #pragma unroll
  for (int off = 32; off > 0; off >>= 1) {
    s  += __shfl_down(s, off);
    s2 += __shfl_down(s2, off);
  }
  __shared__ float rs[4], rs2[4];
  int wid = threadIdx.x >> 6;
  if ((threadIdx.x & 63) == 0) { rs[wid] = s; rs2[wid] = s2; }
  __syncthreads();
  if (threadIdx.x == 0) {
    pstats[bgq * 2]     = rs[0] + rs[1] + rs[2] + rs[3];
    pstats[bgq * 2 + 1] = rs2[0] + rs2[1] + rs2[2] + rs2[3];
  }
}

// ---------------- K2: normalize + transpose -> ht[b][s][c] (bf16); combines partial stats ----------------
__global__ __launch_bounds__(256) void gn_apply_k(const float* __restrict__ x,
                                                  const float* __restrict__ pstats,
                                                  const float* __restrict__ nw,
                                                  const float* __restrict__ nb,
                                                  unsigned short* __restrict__ ht) {
  int st = blockIdx.x, ct = blockIdx.y, b = blockIdx.z;
  int c0 = ct * 64, s0 = st * 64;
  __shared__ unsigned short lds[64][72];
  for (int idx = threadIdx.x; idx < 1024; idx += 256) {
    int row = idx >> 4, c4 = idx & 15;
    int c = c0 + row;
    int gi = (b * NG + (c >> 4)) * 4;
    const float4* pq = (const float4*)(pstats + gi * 2);
    float4 p01 = pq[0], p23 = pq[1];
    float sum = p01.x + p01.z + p23.x + p23.z;
    float ssq = p01.y + p01.w + p23.y + p23.w;
    float inv_n = 1.0f / (CPG * NS);
    float mu = sum * inv_n;
    float var = ssq * inv_n - mu * mu;
    float rstd = rsqrtf(var + 1e-5f);
    float sw = nw[c] * rstd;
    float sb = nb[c] - mu * sw;
    float4 v = *(const float4*)(x + ((size_t)b * NC + c) * NS + s0 + c4 * 4);
    ushort4 u = make_ushort4(f2bf(v.x * sw + sb), f2bf(v.y * sw + sb),
                             f2bf(v.z * sw + sb), f2bf(v.w * sw + sb));
    *(ushort4*)&lds[row][c4 * 4] = u;
  }
  __syncthreads();
  for (int idx = threadIdx.x; idx < 1024; idx += 256) {
    int i = idx >> 4, ch = idx & 15;
    ushort4 u = make_ushort4(lds[ch * 4 + 0][i], lds[ch * 4 + 1][i],
                             lds[ch * 4 + 2][i], lds[ch * 4 + 3][i]);
    *(ushort4*)(ht + ((size_t)b * NS + s0 + i) * NC + c0 + ch * 4) = u;
  }
}

// ---------------- K3: QKV GEMM, global_load_lds staging (BK=64, XOR-swizzled LDS) ----------------
__global__ __launch_bounds__(256) void qkv_gemm_k(const unsigned short* __restrict__ ht,
                                                  const unsigned short* __restrict__ wqb,
                                                  const float* __restrict__ bq,
                                                  unsigned short* __restrict__ qk,
                                                  unsigned short* __restrict__ vt) {
  int b = blockIdx.z;
  int m0 = blockIdx.x * 128, n0 = blockIdx.y * 128;  // m = s, n = o
  __shared__ unsigned short alds[128 * 64];
  __shared__ unsigned short blds[128 * 64];
  const unsigned short* A = ht + (size_t)b * NS * NC;
  int tid = threadIdx.x;
  int l = tid & 63, w = tid >> 6;
  int wr = w >> 1, wc = w & 1;
  int lm = l & 15, lg = l >> 4;
  int lrow = l >> 3, lcb = l & 7;
  f32x4 acc[4][4];
  #pragma unroll
  for (int mi = 0; mi < 4; mi++)
    #pragma unroll
    for (int ni = 0; ni < 4; ni++) acc[mi][ni] = (f32x4){0.f, 0.f, 0.f, 0.f};

  for (int k0 = 0; k0 < NC; k0 += 64) {
    #pragma unroll
    for (int j = 0; j < 4; j++) {
      int row = w * 32 + j * 8 + lrow;
      int scb = lcb ^ (row & 7);
      gload16(A   + (size_t)(m0 + row) * NC + k0 + scb * 8, &alds[(w * 4 + j) * 512]);
      gload16(wqb + (size_t)(n0 + row) * NC + k0 + scb * 8, &blds[(w * 4 + j) * 512]);
    }
    __syncthreads();
    #pragma unroll
    for (int ks = 0; ks < 2; ks++) {
      bf16x8 af[4], bfr[4];
      #pragma unroll
      for (int mi = 0; mi < 4; mi++) {
        int row = wr * 64 + mi * 16 + lm;
        af[mi] = *(const bf16x8*)&alds[((row << 6) + (ks << 5) + (lg << 3)) ^ ((row & 7) << 3)];
      }
      #pragma unroll
      for (int ni = 0; ni < 4; ni++) {
        int row = wc * 64 + ni * 16 + lm;
        bfr[ni] = *(const bf16x8*)&blds[((row << 6) + (ks << 5) + (lg << 3)) ^ ((row & 7) << 3)];
      }
      #pragma unroll
      for (int mi = 0; mi < 4; mi++)
        #pragma unroll
        for (int ni = 0; ni < 4; ni++)
          acc[mi][ni] = __builtin_amdgcn_mfma_f32_16x16x32_bf16(af[mi], bfr[ni], acc[mi][ni], 0, 0, 0);
    }
    __syncthreads();
  }
  if (n0 < QKC) {
    #pragma unroll
    for (int mi = 0; mi < 4; mi++) {
      #pragma unroll
      for (int ni = 0; ni < 4; ni++) {
        int o = n0 + wc * 64 + ni * 16 + lm;
        float bias = bq[o];
        if (o < NC) bias *= CQF;  // Q rows: weight pre-scaled, bias scaled to match
        #pragma unroll
        for (int q = 0; q < 4; q++) {
          int s = m0 + wr * 64 + mi * 16 + lg * 4 + q;
          qk[((size_t)b * NS + s) * QKC + o] = f2bf(acc[mi][ni][q] + bias);
        }
      }
    }
  } else {
    #pragma unroll
    for (int mi = 0; mi < 4; mi++) {
      int s0 = m0 + wr * 64 + mi * 16 + lg * 4;
      #pragma unroll
      for (int ni = 0; ni < 4; ni++) {
        int o = n0 + wc * 64 + ni * 16 + lm;
        float bias = bq[o];
        int dg = o - QKC;  // 0..511 == h*64+d
        ushort4 u = make_ushort4(f2bf(acc[mi][ni][0] + bias), f2bf(acc[mi][ni][1] + bias),
                                 f2bf(acc[mi][ni][2] + bias), f2bf(acc[mi][ni][3] + bias));
        *(ushort4*)(vt + ((size_t)b * NC + dg) * NS + s0) = u;
      }
    }
  }
}

// ---------------- K4: flash attention (32x32x16 MFMA, in-register P, T15 double-pipeline) ----------------
// (R8 version — best measured: 178 us, MfmaUtil 45%.)
__global__ __launch_bounds__(256) void attn_k(const unsigned short* __restrict__ qk,
                                              const unsigned short* __restrict__ vt,
                                              unsigned short* __restrict__ ob) {
  int qt = blockIdx.x, h = blockIdx.y, b = blockIdx.z;
  int tid = threadIdx.x;
  int l = tid & 63, w = tid >> 6;
  int l31 = l & 31, hi = l >> 5;
  __shared__ unsigned short slds[16384];  // [buf:2][K|V][64x64 shorts] = 32 KB
  const unsigned short* qkb = qk + (size_t)b * NS * QKC;
  const unsigned short* vtb = vt + ((size_t)b * NC + h * HD) * NS;
  int iw = qt * 128 + w * 32;

  bf16x8 fq[4];
  #pragma unroll
  for (int kk = 0; kk < 4; kk++)
    fq[kk] = *(const bf16x8*)(qkb + (size_t)(iw + l31) * QKC + h * HD + kk * 16 + hi * 8);

  bf16x8 ones;
  #pragma unroll
  for (int e = 0; e < 8; e++) ones[e] = (short)0x3F80;

  int rb = (((l31 << 6) + (hi << 3)) ^ ((l31 & 7) << 3));
  int rbk[4] = { rb, rb ^ 16, rb ^ 32, rb ^ 48 };

  int sr = tid >> 3, sch = (tid & 7) * 8;
  const unsigned short* kp0 = qkb + NC + h * HD + (size_t)sr * QKC + sch;
  const unsigned short* kp1 = kp0 + (size_t)32 * QKC;
  const unsigned short* vp0 = vtb + (size_t)sr * NS + sch;
  const unsigned short* vp1 = vp0 + (size_t)32 * NS;
  int dk0 = (((sr << 6) + sch) ^ ((sr & 7) << 3));
  int dk1 = ((((sr + 32) << 6) + sch) ^ ((sr & 7) << 3));

  f32x16 acc_o0 = {}, acc_o1 = {}, acc_l = {};

  bf16x8 vA[8], vB[8], pA[4], pB[4];
  #pragma unroll
  for (int e = 0; e < 8; e++) vB[e] = (bf16x8){0, 0, 0, 0, 0, 0, 0, 0};
  #pragma unroll
  for (int e = 0; e < 4; e++) pB[e] = (bf16x8){0, 0, 0, 0, 0, 0, 0, 0};

  uint4 rk0 = *(const uint4*)kp0, rk1 = *(const uint4*)kp1;
  uint4 rv0 = *(const uint4*)vp0, rv1 = *(const uint4*)vp1;
  *(uint4*)&slds[dk0] = rk0;        *(uint4*)&slds[dk1] = rk1;
  *(uint4*)&slds[4096 + dk0] = rv0; *(uint4*)&slds[4096 + dk1] = rv1;
  kp0 += (size_t)64 * QKC; kp1 += (size_t)64 * QKC; vp0 += 64; vp1 += 64;
  rk0 = *(const uint4*)kp0; rk1 = *(const uint4*)kp1;
  rv0 = *(const uint4*)vp0; rv1 = *(const uint4*)vp1;
  __syncthreads();

  #define CVTSW(SA, q, DST) {                                                       \
    unsigned X0, X1, Y0, Y1;                                                        \
    asm("v_cvt_pk_bf16_f32 %0, %1, %2" : "=v"(X0) : "v"(SA[q*8+0]), "v"(SA[q*8+1]));\
    asm("v_cvt_pk_bf16_f32 %0, %1, %2" : "=v"(X1) : "v"(SA[q*8+2]), "v"(SA[q*8+3]));\
    asm("v_cvt_pk_bf16_f32 %0, %1, %2" : "=v"(Y0) : "v"(SA[q*8+4]), "v"(SA[q*8+5]));\
    asm("v_cvt_pk_bf16_f32 %0, %1, %2" : "=v"(Y1) : "v"(SA[q*8+6]), "v"(SA[q*8+7]));\
    asm("v_permlane32_swap_b32 %0, %1" : "+v"(X0), "+v"(Y0));                       \
    asm("v_permlane32_swap_b32 %0, %1" : "+v"(X1), "+v"(Y1));                       \
    union { unsigned u[4]; bf16x8 v; } pu = {{X0, X1, Y0, Y1}};                     \
    DST = pu.v; }

  #define TILE(BUF, t, VN, VP, PN, PP) {                                            \
    *(uint4*)&slds[(BUF^1)*8192 + dk0] = rk0;                                       \
    *(uint4*)&slds[(BUF^1)*8192 + dk1] = rk1;                                       \
    *(uint4*)&slds[(BUF^1)*8192 + 4096 + dk0] = rv0;                                \
    *(uint4*)&slds[(BUF^1)*8192 + 4096 + dk1] = rv1;                                \
    if ((t) + 2 < 64) {                                                             \
      kp0 += (size_t)64 * QKC; kp1 += (size_t)64 * QKC; vp0 += 64; vp1 += 64;       \
      rk0 = *(const uint4*)kp0; rk1 = *(const uint4*)kp1;                           \
      rv0 = *(const uint4*)vp0; rv1 = *(const uint4*)vp1;                           \
    }                                                                               \
    const unsigned short* Kr = &slds[(BUF)*8192];                                   \
    const unsigned short* Vr = &slds[(BUF)*8192 + 4096];                            \
    f32x16 sa0 = {}, sa1 = {};                                                      \
    __builtin_amdgcn_s_setprio(1);                                                  \
    _Pragma("unroll")                                                               \
    for (int kk = 0; kk < 4; kk++) {                                                \
      bf16x8 ak = *(const bf16x8*)&Kr[rbk[kk]];                                     \
      sa0 = __builtin_amdgcn_mfma_f32_32x32x16_bf16(ak, fq[kk], sa0, 0, 0, 0);      \
    }                                                                               \
    _Pragma("unroll")                                                               \
    for (int kk = 0; kk < 4; kk++) {                                                \
      bf16x8 ak = *(const bf16x8*)&Kr[rbk[kk] + 2048];                              \
      sa1 = __builtin_amdgcn_mfma_f32_32x32x16_bf16(ak, fq[kk], sa1, 0, 0, 0);      \
    }                                                                               \
    _Pragma("unroll")                                                               \
    for (int kk = 0; kk < 4; kk++) {                                                \
      VN[kk]     = *(const bf16x8*)&Vr[rbk[kk]];                                    \
      VN[kk + 4] = *(const bf16x8*)&Vr[rbk[kk] + 2048];                             \
    }                                                                               \
    _Pragma("unroll")                                                               \
    for (int bq_ = 0; bq_ < 4; bq_++) {                                             \
      acc_l  = __builtin_amdgcn_mfma_f32_32x32x16_bf16(PP[bq_], ones, acc_l, 0, 0, 0);        \
      acc_o0 = __builtin_amdgcn_mfma_f32_32x32x16_bf16(PP[bq_], VP[bq_], acc_o0, 0, 0, 0);    \
      acc_o1 = __builtin_amdgcn_mfma_f32_32x32x16_bf16(PP[bq_], VP[bq_ + 4], acc_o1, 0, 0, 0);\
    }                                                                               \
    __builtin_amdgcn_s_setprio(0);                                                  \
    _Pragma("unroll")                                                               \
    for (int r = 0; r < 16; r++) {                                                  \
      sa0[r] = __builtin_amdgcn_exp2f(sa0[r]);                                      \
      sa1[r] = __builtin_amdgcn_exp2f(sa1[r]);                                      \
    }                                                                               \
    CVTSW(sa0, 0, PN[0]);                                                           \
    CVTSW(sa0, 1, PN[1]);                                                           \
    CVTSW(sa1, 0, PN[2]);                                                           \
    CVTSW(sa1, 1, PN[3]);                                                           \
    __syncthreads(); }

  for (int t = 0; t < 64; t += 2) {
    TILE(0, t,     vA, vB, pA, pB)
    TILE(1, t + 1, vB, vA, pB, pA)
  }
  #undef TILE
  #undef CVTSW

  #pragma unroll
  for (int bq_ = 0; bq_ < 4; bq_++) {
    acc_l  = __builtin_amdgcn_mfma_f32_32x32x16_bf16(pB[bq_], ones, acc_l, 0, 0, 0);
    acc_o0 = __builtin_amdgcn_mfma_f32_32x32x16_bf16(pB[bq_], vB[bq_], acc_o0, 0, 0, 0);
    acc_o1 = __builtin_amdgcn_mfma_f32_32x32x16_bf16(pB[bq_], vB[bq_ + 4], acc_o1, 0, 0, 0);
  }

  #pragma unroll
  for (int r = 0; r < 16; r++) {
    float inv = __builtin_amdgcn_rcpf(acc_l[r]);
    int i = (r & 3) + 8 * (r >> 2) + 4 * hi;
    size_t rowo = ((size_t)b * NS + (iw + i)) * NC + h * HD;
    ob[rowo + l31]      = f2bf_rn(acc_o0[r] * inv);
    ob[rowo + 32 + l31] = f2bf_rn(acc_o1[r] * inv);
  }
}

// ---------------- K5: proj GEMM + bias + residual (global_load_lds staging, BK=64) ----------------
__global__ __launch_bounds__(256) void proj_gemm_k(const unsigned short* __restrict__ wpb,
                                                   const float* __restrict__ bp,
                                                   const unsigned short* __restrict__ obuf,
                                                   const float* __restrict__ x,
                                                   float* __restrict__ out) {
  int b = blockIdx.z;
  int m0 = blockIdx.x * 128, n0 = blockIdx.y * 128;  // m = o, n = s
  __shared__ unsigned short alds[128 * 64];
  __shared__ unsigned short blds[128 * 64];
  const unsigned short* Bt = obuf + (size_t)b * NS * NC;
  int tid = threadIdx.x;
  int l = tid & 63, w = tid >> 6;
  int wr = w >> 1, wc = w & 1;
  int lm = l & 15, lg = l >> 4;
  int lrow = l >> 3, lcb = l & 7;
  f32x4 acc[4][4];
  #pragma unroll
  for (int mi = 0; mi < 4; mi++)
    #pragma unroll
    for (int ni = 0; ni < 4; ni++) acc[mi][ni] = (f32x4){0.f, 0.f, 0.f, 0.f};

  for (int k0 = 0; k0 < NC; k0 += 64) {
    #pragma unroll
    for (int j = 0; j < 4; j++) {
      int row = w * 32 + j * 8 + lrow;
      int scb = lcb ^ (row & 7);
      gload16(wpb + (size_t)(m0 + row) * NC + k0 + scb * 8, &alds[(w * 4 + j) * 512]);
      gload16(Bt  + (size_t)(n0 + row) * NC + k0 + scb * 8, &blds[(w * 4 + j) * 512]);
    }
    __syncthreads();
    #pragma unroll
    for (int ks = 0; ks < 2; ks++) {
      bf16x8 af[4], bfr[4];
      #pragma unroll
      for (int mi = 0; mi < 4; mi++) {
        int row = wr * 64 + mi * 16 + lm;
        af[mi] = *(const bf16x8*)&alds[((row << 6) + (ks << 5) + (lg << 3)) ^ ((row & 7) << 3)];
      }
      #pragma unroll
      for (int ni = 0; ni < 4; ni++) {
        int row = wc * 64 + ni * 16 + lm;
        bfr[ni] = *(const bf16x8*)&blds[((row << 6) + (ks << 5) + (lg << 3)) ^ ((row & 7) << 3)];
      }
      #pragma unroll
      for (int mi = 0; mi < 4; mi++)
        #pragma unroll
        for (int ni = 0; ni < 4; ni++)
          acc[mi][ni] = __builtin_amdgcn_mfma_f32_16x16x32_bf16(af[mi], bfr[ni], acc[mi][ni], 0, 0, 0);
    }
    __syncthreads();
  }
  #pragma unroll
  for (int mi = 0; mi < 4; mi++) {
    #pragma unroll
    for (int q = 0; q < 4; q++) {
      int o = m0 + wr * 64 + mi * 16 + lg * 4 + q;
      float bias = bp[o];
      #pragma unroll
      for (int ni = 0; ni < 4; ni++) {
        int s = n0 + wc * 64 + ni * 16 + lm;
        size_t idx = ((size_t)b * NC + o) * NS + s;
        out[idx] = acc[mi][ni][q] + bias + x[idx];
      }
    }
  }
}

extern "C" void kernel_launch(void* const* d_in, const int* in_sizes, int n_in,
                              void* d_out, int out_size, void* d_ws, size_t ws_size,
                              hipStream_t stream) {
  const float* x  = (const float*)d_in[0];
  const float* nw = (const float*)d_in[1];
  const float* nb = (const float*)d_in[2];
  const float* wq = (const float*)d_in[3];
  const float* bq = (const float*)d_in[4];
  const float* wp = (const float*)d_in[5];
  const float* bp = (const float*)d_in[6];
  float* out = (float*)d_out;

  char* ws = (char*)d_ws;
  size_t off = 0;
  off += 1024;  // (legacy stats slot, unused)
  unsigned short* ht  = (unsigned short*)(ws + off); off += (size_t)NB * NS * NC * 2;   // 16.78 MB
  unsigned short* qk  = (unsigned short*)(ws + off); off += (size_t)NB * NS * QKC * 2;  // 33.55 MB
  unsigned short* vt  = (unsigned short*)(ws + off); off += (size_t)NB * NS * NC * 2;   // 16.78 MB
  unsigned short* wqb = (unsigned short*)(ws + off); off += (size_t)3 * NC * NC * 2;    // 1.57 MB
  unsigned short* wpb = (unsigned short*)(ws + off); off += (size_t)NC * NC * 2;        // 0.52 MB
  unsigned short* ob  = ht;          // lifetime-disjoint alias
  float* pstats = (float*)qk;        // lifetime-disjoint: used before qkv_gemm writes qk

  const int nq8 = 3 * NC * NC / 8, np8 = NC * NC / 8;
  wprep_k<<<dim3((nq8 + np8 + 255) / 256), 256, 0, stream>>>(
      wq, wp, wqb, wpb, nq8, np8, NC * NC / 8);
  gn_stats_k<<<dim3(NB * NG * 4), 256, 0, stream>>>(x, pstats);
  gn_apply_k<<<dim3(NS / 64, NC / 64, NB), 256, 0, stream>>>(x, pstats, nw, nb, ht);
  qkv_gemm_k<<<dim3(NS / 128, 1536 / 128, NB), 256, 0, stream>>>(ht, wqb, bq, qk, vt);
  attn_k<<<dim3(NS / 128, NH, NB), 256, 0, stream>>>(qk, vt, ob);
  proj_gemm_k<<<dim3(NC / 128, NS / 128, NB), 256, 0, stream>>>(wpb, bp, ob, x, out);
}

// Round 12
// 219.341 us; speedup vs baseline: 1.1366x; 1.1249x over previous
//
#include <hip/hip_runtime.h>
#include <hip/hip_bf16.h>

#define NB 4
#define NC 512
#define NS 4096
#define NH 8
#define HD 64
#define NG 32
#define CPG 16
#define QKC 1024   // Q+K channels in qk buffer
#define CQF 0.18033688f  // 0.125 * log2(e), folded into Q weights

typedef __attribute__((ext_vector_type(8))) short bf16x8;
typedef __attribute__((ext_vector_type(4))) float f32x4;
typedef __attribute__((ext_vector_type(16))) float f32x16;

__device__ __forceinline__ unsigned short f2bf(float f) {
  union { float f; unsigned int u; } v; v.f = f;
  unsigned int r = v.u + 0x7FFFu + ((v.u >> 16) & 1u);
  return (unsigned short)(r >> 16);
}

__device__ __forceinline__ unsigned short f2bf_rn(float f) {
  union { __hip_bfloat16 h; unsigned short u; } cv;
  cv.h = __float2bfloat16(f);
  return cv.u;
}

// async global->LDS, 16B per lane. LDS base must be wave-uniform; source is per-lane.
__device__ __forceinline__ void gload16(const unsigned short* g, unsigned short* s) {
  __builtin_amdgcn_global_load_lds(
      (const __attribute__((address_space(1))) unsigned int*)g,
      (__attribute__((address_space(3))) unsigned int*)s, 16, 0, 0);
}

// ---------------- K1: fused prep: gn partial stats (blocks 0..511) + weight cvt (blocks 512..1023) ----------------
__global__ __launch_bounds__(256) void prep_k(const float* __restrict__ x,
                                              float* __restrict__ pstats,
                                              const float* __restrict__ wq,
                                              const float* __restrict__ wp,
                                              unsigned short* __restrict__ wqb,
                                              unsigned short* __restrict__ wpb) {
  int bid = blockIdx.x;
  if (bid < NB * NG * 4) {
    int bgq = bid;
    const float4* xp = (const float4*)(x + (size_t)bgq * (CPG * NS / 4));
    float s = 0.f, s2 = 0.f;
    #pragma unroll 4
    for (int i = threadIdx.x; i < CPG * NS / 16; i += 256) {
      float4 v = xp[i];
      s  += v.x + v.y + v.z + v.w;
      s2 += v.x * v.x + v.y * v.y + v.z * v.z + v.w * v.w;
    }
    #pragma unroll
    for (int off = 32; off > 0; off >>= 1) {
      s  += __shfl_down(s, off);
      s2 += __shfl_down(s2, off);
    }
    __shared__ float rs[4], rs2[4];
    int wid = threadIdx.x >> 6;
    if ((threadIdx.x & 63) == 0) { rs[wid] = s; rs2[wid] = s2; }
    __syncthreads();
    if (threadIdx.x == 0) {
      pstats[bgq * 2]     = rs[0] + rs[1] + rs[2] + rs[3];
      pstats[bgq * 2 + 1] = rs2[0] + rs2[1] + rs2[2] + rs2[3];
    }
  } else {
    const int nq8 = 3 * NC * NC / 8, np8 = NC * NC / 8, se8 = NC * NC / 8;
    int i = (bid - NB * NG * 4) * 256 + threadIdx.x;
    if (i >= nq8 + np8) return;
    const float* src;
    unsigned short* dst;
    float sc;
    int j;
    if (i < nq8) { src = wq; dst = wqb; j = i; sc = (i < se8) ? CQF : 1.0f; }
    else         { src = wp; dst = wpb; j = i - nq8; sc = 1.0f; }
    const float4* s = (const float4*)src + (size_t)j * 2;
    float4 a = s[0], b = s[1];
    ushort4 u0 = make_ushort4(f2bf_rn(a.x * sc), f2bf_rn(a.y * sc),
                              f2bf_rn(a.z * sc), f2bf_rn(a.w * sc));
    ushort4 u1 = make_ushort4(f2bf_rn(b.x * sc), f2bf_rn(b.y * sc),
                              f2bf_rn(b.z * sc), f2bf_rn(b.w * sc));
    uint4 o;
    o.x = (unsigned)u0.x | ((unsigned)u0.y << 16);
    o.y = (unsigned)u0.z | ((unsigned)u0.w << 16);
    o.z = (unsigned)u1.x | ((unsigned)u1.y << 16);
    o.w = (unsigned)u1.z | ((unsigned)u1.w << 16);
    *((uint4*)dst + j) = o;
  }
}

// ---------------- K2: normalize + transpose -> ht[b][s][c] (bf16); combines partial stats ----------------
__global__ __launch_bounds__(256) void gn_apply_k(const float* __restrict__ x,
                                                  const float* __restrict__ pstats,
                                                  const float* __restrict__ nw,
                                                  const float* __restrict__ nb,
                                                  unsigned short* __restrict__ ht) {
  int st = blockIdx.x, ct = blockIdx.y, b = blockIdx.z;
  int c0 = ct * 64, s0 = st * 64;
  __shared__ unsigned short lds[64][72];
  for (int idx = threadIdx.x; idx < 1024; idx += 256) {
    int row = idx >> 4, c4 = idx & 15;
    int c = c0 + row;
    int gi = (b * NG + (c >> 4)) * 4;
    const float4* pq = (const float4*)(pstats + gi * 2);
    float4 p01 = pq[0], p23 = pq[1];
    float sum = p01.x + p01.z + p23.x + p23.z;
    float ssq = p01.y + p01.w + p23.y + p23.w;
    float inv_n = 1.0f / (CPG * NS);
    float mu = sum * inv_n;
    float var = ssq * inv_n - mu * mu;
    float rstd = rsqrtf(var + 1e-5f);
    float sw = nw[c] * rstd;
    float sb = nb[c] - mu * sw;
    float4 v = *(const float4*)(x + ((size_t)b * NC + c) * NS + s0 + c4 * 4);
    ushort4 u = make_ushort4(f2bf(v.x * sw + sb), f2bf(v.y * sw + sb),
                             f2bf(v.z * sw + sb), f2bf(v.w * sw + sb));
    *(ushort4*)&lds[row][c4 * 4] = u;
  }
  __syncthreads();
  for (int idx = threadIdx.x; idx < 1024; idx += 256) {
    int i = idx >> 4, ch = idx & 15;
    ushort4 u = make_ushort4(lds[ch * 4 + 0][i], lds[ch * 4 + 1][i],
                             lds[ch * 4 + 2][i], lds[ch * 4 + 3][i]);
    *(ushort4*)(ht + ((size_t)b * NS + s0 + i) * NC + c0 + ch * 4) = u;
  }
}

// ---------------- K3: QKV GEMM, global_load_lds staging (BK=64, XOR-swizzled LDS) ----------------
__global__ __launch_bounds__(256) void qkv_gemm_k(const unsigned short* __restrict__ ht,
                                                  const unsigned short* __restrict__ wqb,
                                                  const float* __restrict__ bq,
                                                  unsigned short* __restrict__ qk,
                                                  unsigned short* __restrict__ vt) {
  int b = blockIdx.z;
  int m0 = blockIdx.x * 128, n0 = blockIdx.y * 128;  // m = s, n = o
  __shared__ unsigned short alds[128 * 64];
  __shared__ unsigned short blds[128 * 64];
  const unsigned short* A = ht + (size_t)b * NS * NC;
  int tid = threadIdx.x;
  int l = tid & 63, w = tid >> 6;
  int wr = w >> 1, wc = w & 1;
  int lm = l & 15, lg = l >> 4;
  int lrow = l >> 3, lcb = l & 7;
  f32x4 acc[4][4];
  #pragma unroll
  for (int mi = 0; mi < 4; mi++)
    #pragma unroll
    for (int ni = 0; ni < 4; ni++) acc[mi][ni] = (f32x4){0.f, 0.f, 0.f, 0.f};

  for (int k0 = 0; k0 < NC; k0 += 64) {
    #pragma unroll
    for (int j = 0; j < 4; j++) {
      int row = w * 32 + j * 8 + lrow;
      int scb = lcb ^ (row & 7);
      gload16(A   + (size_t)(m0 + row) * NC + k0 + scb * 8, &alds[(w * 4 + j) * 512]);
      gload16(wqb + (size_t)(n0 + row) * NC + k0 + scb * 8, &blds[(w * 4 + j) * 512]);
    }
    __syncthreads();
    #pragma unroll
    for (int ks = 0; ks < 2; ks++) {
      bf16x8 af[4], bfr[4];
      #pragma unroll
      for (int mi = 0; mi < 4; mi++) {
        int row = wr * 64 + mi * 16 + lm;
        af[mi] = *(const bf16x8*)&alds[((row << 6) + (ks << 5) + (lg << 3)) ^ ((row & 7) << 3)];
      }
      #pragma unroll
      for (int ni = 0; ni < 4; ni++) {
        int row = wc * 64 + ni * 16 + lm;
        bfr[ni] = *(const bf16x8*)&blds[((row << 6) + (ks << 5) + (lg << 3)) ^ ((row & 7) << 3)];
      }
      #pragma unroll
      for (int mi = 0; mi < 4; mi++)
        #pragma unroll
        for (int ni = 0; ni < 4; ni++)
          acc[mi][ni] = __builtin_amdgcn_mfma_f32_16x16x32_bf16(af[mi], bfr[ni], acc[mi][ni], 0, 0, 0);
    }
    __syncthreads();
  }
  if (n0 < QKC) {
    #pragma unroll
    for (int mi = 0; mi < 4; mi++) {
      #pragma unroll
      for (int ni = 0; ni < 4; ni++) {
        int o = n0 + wc * 64 + ni * 16 + lm;
        float bias = bq[o];
        if (o < NC) bias *= CQF;  // Q rows: weight pre-scaled, bias scaled to match
        #pragma unroll
        for (int q = 0; q < 4; q++) {
          int s = m0 + wr * 64 + mi * 16 + lg * 4 + q;
          qk[((size_t)b * NS + s) * QKC + o] = f2bf(acc[mi][ni][q] + bias);
        }
      }
    }
  } else {
    #pragma unroll
    for (int mi = 0; mi < 4; mi++) {
      int s0 = m0 + wr * 64 + mi * 16 + lg * 4;
      #pragma unroll
      for (int ni = 0; ni < 4; ni++) {
        int o = n0 + wc * 64 + ni * 16 + lm;
        float bias = bq[o];
        int dg = o - QKC;  // 0..511 == h*64+d
        ushort4 u = make_ushort4(f2bf(acc[mi][ni][0] + bias), f2bf(acc[mi][ni][1] + bias),
                                 f2bf(acc[mi][ni][2] + bias), f2bf(acc[mi][ni][3] + bias));
        *(ushort4*)(vt + ((size_t)b * NC + dg) * NS + s0) = u;
      }
    }
  }
}

// ---------------- K4: flash attention ----------------
// 8 waves / 256 Q-rows per block; gload_lds staging (pre-swizzled source, linear dest);
// XCD-aware block mapping: all 16 qt-blocks of one (b,h) on one XCD (K/V fits 4MB L2).
__global__ __launch_bounds__(512) void attn_k(const unsigned short* __restrict__ qk,
                                              const unsigned short* __restrict__ vt,
                                              unsigned short* __restrict__ ob) {
  int bid = blockIdx.x;
  int xcd = bid & 7, g = bid >> 3;
  int pair = xcd * 4 + (g >> 4);   // bijective: 32 (b,h) pairs, 4 per XCD
  int qt = g & 15;
  int h = pair & 7, b = pair >> 3;
  int tid = threadIdx.x;
  int l = tid & 63, w = tid >> 6;  // w in 0..7
  int l31 = l & 31, hi = l >> 5;
  __shared__ unsigned short slds[16384];  // [buf:2][K|V][64x64 shorts] = 32 KB
  const unsigned short* qkb = qk + (size_t)b * NS * QKC;
  const unsigned short* vtb = vt + ((size_t)b * NC + h * HD) * NS;
  int iw = qt * 256 + w * 32;

  bf16x8 fq[4];
  #pragma unroll
  for (int kk = 0; kk < 4; kk++)
    fq[kk] = *(const bf16x8*)(qkb + (size_t)(iw + l31) * QKC + h * HD + kk * 16 + hi * 8);

  bf16x8 ones;
  #pragma unroll
  for (int e = 0; e < 8; e++) ones[e] = (short)0x3F80;

  int rb = (((l31 << 6) + (hi << 3)) ^ ((l31 & 7) << 3));
  int rbk[4] = { rb, rb ^ 16, rb ^ 32, rb ^ 48 };

  // gload staging: wave w covers rows w*8..w*8+8; lane l -> row kr, source col16 pre-swizzled
  int kr = w * 8 + (l >> 3);
  int scb = (l & 7) ^ (l >> 3);    // (l&7) ^ (kr&7), since kr&7 == l>>3
  const unsigned short* kgp = qkb + NC + h * HD + (size_t)kr * QKC + scb * 8;
  const unsigned short* vgp = vtb + (size_t)kr * NS + scb * 8;
  unsigned short* kdA = &slds[w * 512];
  unsigned short* kdB = &slds[8192 + w * 512];
  unsigned short* vdA = &slds[4096 + w * 512];
  unsigned short* vdB = &slds[12288 + w * 512];

  f32x16 acc_o0 = {}, acc_o1 = {}, acc_l = {};

  bf16x8 vA[8], vB[8], pA[4], pB[4];
  #pragma unroll
  for (int e = 0; e < 8; e++) vB[e] = (bf16x8){0, 0, 0, 0, 0, 0, 0, 0};
  #pragma unroll
  for (int e = 0; e < 4; e++) pB[e] = (bf16x8){0, 0, 0, 0, 0, 0, 0, 0};

  // prologue: tile0 -> buf A
  gload16(kgp, kdA);
  gload16(vgp, vdA);
  kgp += (size_t)64 * QKC; vgp += 64;
  asm volatile("s_waitcnt vmcnt(0)" ::: "memory");
  __syncthreads();

  #define CVTSW(SA, q, DST) {                                                       \
    unsigned X0, X1, Y0, Y1;                                                        \
    asm("v_cvt_pk_bf16_f32 %0, %1, %2" : "=v"(X0) : "v"(SA[q*8+0]), "v"(SA[q*8+1]));\
    asm("v_cvt_pk_bf16_f32 %0, %1, %2" : "=v"(X1) : "v"(SA[q*8+2]), "v"(SA[q*8+3]));\
    asm("v_cvt_pk_bf16_f32 %0, %1, %2" : "=v"(Y0) : "v"(SA[q*8+4]), "v"(SA[q*8+5]));\
    asm("v_cvt_pk_bf16_f32 %0, %1, %2" : "=v"(Y1) : "v"(SA[q*8+6]), "v"(SA[q*8+7]));\
    asm("v_permlane32_swap_b32 %0, %1" : "+v"(X0), "+v"(Y0));                       \
    asm("v_permlane32_swap_b32 %0, %1" : "+v"(X1), "+v"(Y1));                       \
    union { unsigned u[4]; bf16x8 v; } pu = {{X0, X1, Y0, Y1}};                     \
    DST = pu.v; }

  // TILE: gload stage(t+1) -> other buf; QK(t); V(t)->VN; PV(t-1) from PP/VP (pure reg);
  //       exp2(t); cvt -> PN; vmcnt-drain + barrier.
  #define TILE(BUF, t, VN, VP, PN, PP, KD, VD) {                                    \
    if ((t) + 1 < 64) {                                                             \
      gload16(kgp, KD);                                                             \
      gload16(vgp, VD);                                                             \
      kgp += (size_t)64 * QKC; vgp += 64;                                           \
    }                                                                               \
    const unsigned short* Kr = &slds[(BUF)*8192];                                   \
    const unsigned short* Vr = &slds[(BUF)*8192 + 4096];                            \
    f32x16 sa0 = {}, sa1 = {};                                                      \
    __builtin_amdgcn_s_setprio(1);                                                  \
    _Pragma("unroll")                                                               \
    for (int kk = 0; kk < 4; kk++) {                                                \
      bf16x8 ak = *(const bf16x8*)&Kr[rbk[kk]];                                     \
      sa0 = __builtin_amdgcn_mfma_f32_32x32x16_bf16(ak, fq[kk], sa0, 0, 0, 0);      \
    }                                                                               \
    _Pragma("unroll")                                                               \
    for (int kk = 0; kk < 4; kk++) {                                                \
      bf16x8 ak = *(const bf16x8*)&Kr[rbk[kk] + 2048];                              \
      sa1 = __builtin_amdgcn_mfma_f32_32x32x16_bf16(ak, fq[kk], sa1, 0, 0, 0);      \
    }                                                                               \
    _Pragma("unroll")                                                               \
    for (int kk = 0; kk < 4; kk++) {                                                \
      VN[kk]     = *(const bf16x8*)&Vr[rbk[kk]];                                    \
      VN[kk + 4] = *(const bf16x8*)&Vr[rbk[kk] + 2048];                             \
    }                                                                               \
    _Pragma("unroll")                                                               \
    for (int bq_ = 0; bq_ < 4; bq_++) {                                             \
      acc_l  = __builtin_amdgcn_mfma_f32_32x32x16_bf16(PP[bq_], ones, acc_l, 0, 0, 0);        \
      acc_o0 = __builtin_amdgcn_mfma_f32_32x32x16_bf16(PP[bq_], VP[bq_], acc_o0, 0, 0, 0);    \
      acc_o1 = __builtin_amdgcn_mfma_f32_32x32x16_bf16(PP[bq_], VP[bq_ + 4], acc_o1, 0, 0, 0);\
    }                                                                               \
    __builtin_amdgcn_s_setprio(0);                                                  \
    _Pragma("unroll")                                                               \
    for (int r = 0; r < 16; r++) {                                                  \
      sa0[r] = __builtin_amdgcn_exp2f(sa0[r]);                                      \
      sa1[r] = __builtin_amdgcn_exp2f(sa1[r]);                                      \
    }                                                                               \
    CVTSW(sa0, 0, PN[0]);                                                           \
    CVTSW(sa0, 1, PN[1]);                                                           \
    CVTSW(sa1, 0, PN[2]);                                                           \
    CVTSW(sa1, 1, PN[3]);                                                           \
    asm volatile("s_waitcnt vmcnt(0)" ::: "memory");                                \
    __syncthreads(); }

  for (int t = 0; t < 64; t += 2) {
    TILE(0, t,     vA, vB, pA, pB, kdB, vdB)
    TILE(1, t + 1, vB, vA, pB, pA, kdA, vdA)
  }
  #undef TILE
  #undef CVTSW

  // epilogue: drain final PV (tile 63 state in pB/vB)
  #pragma unroll
  for (int bq_ = 0; bq_ < 4; bq_++) {
    acc_l  = __builtin_amdgcn_mfma_f32_32x32x16_bf16(pB[bq_], ones, acc_l, 0, 0, 0);
    acc_o0 = __builtin_amdgcn_mfma_f32_32x32x16_bf16(pB[bq_], vB[bq_], acc_o0, 0, 0, 0);
    acc_o1 = __builtin_amdgcn_mfma_f32_32x32x16_bf16(pB[bq_], vB[bq_ + 4], acc_o1, 0, 0, 0);
  }

  #pragma unroll
  for (int r = 0; r < 16; r++) {
    float inv = __builtin_amdgcn_rcpf(acc_l[r]);
    int i = (r & 3) + 8 * (r >> 2) + 4 * hi;
    size_t rowo = ((size_t)b * NS + (iw + i)) * NC + h * HD;
    ob[rowo + l31]      = f2bf_rn(acc_o0[r] * inv);
    ob[rowo + 32 + l31] = f2bf_rn(acc_o1[r] * inv);
  }
}

// ---------------- K5: proj GEMM + bias + residual (global_load_lds staging, BK=64) ----------------
__global__ __launch_bounds__(256) void proj_gemm_k(const unsigned short* __restrict__ wpb,
                                                   const float* __restrict__ bp,
                                                   const unsigned short* __restrict__ obuf,
                                                   const float* __restrict__ x,
                                                   float* __restrict__ out) {
  int b = blockIdx.z;
  int m0 = blockIdx.x * 128, n0 = blockIdx.y * 128;  // m = o, n = s
  __shared__ unsigned short alds[128 * 64];
  __shared__ unsigned short blds[128 * 64];
  const unsigned short* Bt = obuf + (size_t)b * NS * NC;
  int tid = threadIdx.x;
  int l = tid & 63, w = tid >> 6;
  int wr = w >> 1, wc = w & 1;
  int lm = l & 15, lg = l >> 4;
  int lrow = l >> 3, lcb = l & 7;
  f32x4 acc[4][4];
  #pragma unroll
  for (int mi = 0; mi < 4; mi++)
    #pragma unroll
    for (int ni = 0; ni < 4; ni++) acc[mi][ni] = (f32x4){0.f, 0.f, 0.f, 0.f};

  for (int k0 = 0; k0 < NC; k0 += 64) {
    #pragma unroll
    for (int j = 0; j < 4; j++) {
      int row = w * 32 + j * 8 + lrow;
      int scb = lcb ^ (row & 7);
      gload16(wpb + (size_t)(m0 + row) * NC + k0 + scb * 8, &alds[(w * 4 + j) * 512]);
      gload16(Bt  + (size_t)(n0 + row) * NC + k0 + scb * 8, &blds[(w * 4 + j) * 512]);
    }
    __syncthreads();
    #pragma unroll
    for (int ks = 0; ks < 2; ks++) {
      bf16x8 af[4], bfr[4];
      #pragma unroll
      for (int mi = 0; mi < 4; mi++) {
        int row = wr * 64 + mi * 16 + lm;
        af[mi] = *(const bf16x8*)&alds[((row << 6) + (ks << 5) + (lg << 3)) ^ ((row & 7) << 3)];
      }
      #pragma unroll
      for (int ni = 0; ni < 4; ni++) {
        int row = wc * 64 + ni * 16 + lm;
        bfr[ni] = *(const bf16x8*)&blds[((row << 6) + (ks << 5) + (lg << 3)) ^ ((row & 7) << 3)];
      }
      #pragma unroll
      for (int mi = 0; mi < 4; mi++)
        #pragma unroll
        for (int ni = 0; ni < 4; ni++)
          acc[mi][ni] = __builtin_amdgcn_mfma_f32_16x16x32_bf16(af[mi], bfr[ni], acc[mi][ni], 0, 0, 0);
    }
    __syncthreads();
  }
  #pragma unroll
  for (int mi = 0; mi < 4; mi++) {
    #pragma unroll
    for (int q = 0; q < 4; q++) {
      int o = m0 + wr * 64 + mi * 16 + lg * 4 + q;
      float bias = bp[o];
      #pragma unroll
      for (int ni = 0; ni < 4; ni++) {
        int s = n0 + wc * 64 + ni * 16 + lm;
        size_t idx = ((size_t)b * NC + o) * NS + s;
        out[idx] = acc[mi][ni][q] + bias + x[idx];
      }
    }
  }
}

extern "C" void kernel_launch(void* const* d_in, const int* in_sizes, int n_in,
                              void* d_out, int out_size, void* d_ws, size_t ws_size,
                              hipStream_t stream) {
  const float* x  = (const float*)d_in[0];
  const float* nw = (const float*)d_in[1];
  const float* nb = (const float*)d_in[2];
  const float* wq = (const float*)d_in[3];
  const float* bq = (const float*)d_in[4];
  const float* wp = (const float*)d_in[5];
  const float* bp = (const float*)d_in[6];
  float* out = (float*)d_out;

  char* ws = (char*)d_ws;
  size_t off = 0;
  off += 1024;  // (legacy stats slot, unused)
  unsigned short* ht  = (unsigned short*)(ws + off); off += (size_t)NB * NS * NC * 2;   // 16.78 MB
  unsigned short* qk  = (unsigned short*)(ws + off); off += (size_t)NB * NS * QKC * 2;  // 33.55 MB
  unsigned short* vt  = (unsigned short*)(ws + off); off += (size_t)NB * NS * NC * 2;   // 16.78 MB
  unsigned short* wqb = (unsigned short*)(ws + off); off += (size_t)3 * NC * NC * 2;    // 1.57 MB
  unsigned short* wpb = (unsigned short*)(ws + off); off += (size_t)NC * NC * 2;        // 0.52 MB
  unsigned short* ob  = ht;          // lifetime-disjoint alias
  float* pstats = (float*)qk;        // lifetime-disjoint: used before qkv_gemm writes qk

  prep_k<<<dim3(1024), 256, 0, stream>>>(x, pstats, wq, wp, wqb, wpb);
  gn_apply_k<<<dim3(NS / 64, NC / 64, NB), 256, 0, stream>>>(x, pstats, nw, nb, ht);
  qkv_gemm_k<<<dim3(NS / 128, 1536 / 128, NB), 256, 0, stream>>>(ht, wqb, bq, qk, vt);
  attn_k<<<dim3(512), 512, 0, stream>>>(qk, vt, ob);
  proj_gemm_k<<<dim3(NC / 128, NS / 128, NB), 256, 0, stream>>>(wpb, bp, ob, x, out);
}